// Round 20
// baseline (81.318 us; speedup 1.0000x reference)
//
#include <hip/hip_runtime.h>
#include <stdint.h>

#define NC 12
#define NHW (256*256)
#define RSTR 136            // LDS floats per tap-row: [3]=haloL, [4..131]=cols, [132]=haloR
#define CSTR 816            // 6*RSTR; %32==16 -> tap reads 2-way (free, m136)

typedef __attribute__((ext_vector_type(8))) short bf16x8;
typedef __attribute__((ext_vector_type(4))) float f32x4;
typedef __attribute__((ext_vector_type(4))) uint32_t u32x4;
typedef __attribute__((ext_vector_type(2))) __bf16 bf16x2v;

// hot-path pack: single v_cvt_pk_bf16_f32
__device__ __forceinline__ uint32_t pkbf(float lo, float hi) {
    uint32_t r;
    asm("v_cvt_pk_bf16_f32 %0, %1, %2" : "=v"(r) : "v"(lo), "v"(hi));
    return r;
}
// cold-path pack (weight setup, once)
__device__ __forceinline__ uint32_t pkbf_c(float lo, float hi) {
    bf16x2v v = { (__bf16)lo, (__bf16)hi };
    return __builtin_bit_cast(uint32_t, v);
}
// opaque "v" pin (r6-verified). NEVER "a" (r12); NEVER (256,4) (r17 spill, r18 miscompile).
#define PIN(v) asm volatile("" : "+v"(v))

// Fused NCA step, LDS-staged 4x128 tile, 1-ahead software pipeline.
// == r19 (80.6us) with ALL s_setprio toggles REMOVED: they are ordering-pinned
// intrinsics that fence the scheduler 32x per wave; this kernel has no wave
// role-split (all waves lockstep same phase), the regime where setprio is
// null-to-negative (m190). Single-variable test of the scheduling-fence theory.
// K-bijections (same on A and B => contraction exact):
//   GEMM1 (w1[96x48]·yT): slot(s,g,j): s=0 -> col 12g+j ; s=1,j<4 -> col 12g+8+j
//   BIAS fold (r11-verified): slot (s=1,g=0,elem4): A=bf16(b1[row]), B=bf16(1.0)
//   GEMM2 (w2[12x96]·hT): slot(s2,g,j) -> col 32s2 + 16*(j>=4) + 4g + (j&3)
// GEMM1's D regs ARE GEMM2's B-frags. GEMM2 M-perm sigma(4g+r)=3g+r:
// acc2[r]'s channel == lane's stencil channel c0+r -> epilogue x = held center tap.
__global__ __launch_bounds__(256, 3) void nca_fused19(
    const float* __restrict__ x, const float* __restrict__ w1,
    const float* __restrict__ b1, const float* __restrict__ w2,
    const float* __restrict__ rmask, float* __restrict__ out)
{
    __shared__ float smem[12 * CSTR];   // 39168 B

    const int tid  = threadIdx.x;
    const int lane = tid & 63;
    const int wv   = tid >> 6;
    const int g    = lane >> 4;   // 16-lane group
    const int p    = lane & 15;   // pixel col (B/D), weight row (A)
    const int c0   = 3 * g;       // lane's stencil/epilogue channel base

    // ---- weight fragments (bias folded into a1u[t][1] elem4), "v"-pinned ----
    u32x4 a1u[6][2];
    #pragma unroll
    for (int t = 0; t < 6; ++t) {
        const int row = 16*t + p;
        const float4 fa = *reinterpret_cast<const float4*>(w1 + row*48 + 12*g + 0);
        const float4 fb = *reinterpret_cast<const float4*>(w1 + row*48 + 12*g + 4);
        const float4 fc = *reinterpret_cast<const float4*>(w1 + row*48 + 12*g + 8);
        const uint32_t biasw = (g == 0) ? pkbf_c(b1[row], 0.f) : 0u;
        a1u[t][0] = (u32x4){ pkbf_c(fa.x, fa.y), pkbf_c(fa.z, fa.w), pkbf_c(fb.x, fb.y), pkbf_c(fb.z, fb.w) };
        a1u[t][1] = (u32x4){ pkbf_c(fc.x, fc.y), pkbf_c(fc.z, fc.w), biasw, 0u };
        PIN(a1u[t][0]); PIN(a1u[t][1]);
    }
    u32x4 a2u[3];
    {
        const int rp = p & 3, gp = p >> 2;
        const int chA = 3*gp + rp;              // sigma(4g+r)=3g+r
        #pragma unroll
        for (int s = 0; s < 3; ++s) {
            u32x4 u = {0u, 0u, 0u, 0u};
            if (rp < 3) {
                const float4 wa = *reinterpret_cast<const float4*>(w2 + chA*96 + 32*s + 4*g);
                const float4 wb = *reinterpret_cast<const float4*>(w2 + chA*96 + 32*s + 16 + 4*g);
                u = (u32x4){ pkbf_c(wa.x, wa.y), pkbf_c(wa.z, wa.w), pkbf_c(wb.x, wb.y), pkbf_c(wb.z, wb.w) };
            }
            a2u[s] = u;
            PIN(a2u[s]);
        }
    }
    const uint32_t one_c = (g == 0) ? 0x00003F80u : 0u;   // elem4 = bf16(1.0), group 0

    // shared zero C-in quad (r19, neutral but harmless)
    f32x4 zacc = {0.f, 0.f, 0.f, 0.f};
    PIN(zacc);

    // grid: 4096 blocks = 32 batches x 64 row-strips x 2 col-halves
    const int b     = blockIdx.x >> 7;
    const int strip = (blockIdx.x >> 1) & 63;
    const int half  = blockIdx.x & 1;
    const int ra    = strip << 2;
    const int c0g   = half << 7;
    const float* __restrict__ xb = x + (size_t)b * NC * NHW;
    const float* __restrict__ mb = rmask + (size_t)b * NHW;
    float* __restrict__ ob = out + (size_t)b * NC * NHW;

    // wave wv owns output row ra+wv
    const int h    = ra + wv;
    const int hrow = h << 8;

    // hoisted bases (before staging so mask prefetch can issue first)
    int tb[3];
    #pragma unroll
    for (int ci = 0; ci < 3; ++ci) tb[ci] = (c0 + ci)*CSTR + wv*RSTR + 3 + p;
    float* obp[3];
    #pragma unroll
    for (int r = 0; r < 3; ++r) obp[r] = ob + (c0 + r)*NHW + hrow + c0g + p;
    const float* mbp = mb + hrow + c0g + p;

    // ---- prefetch ALL 8 mask values (global, ~900cy) before anything else ----
    float mv[8];
    #pragma unroll
    for (int m = 0; m < 8; ++m) mv[m] = mbp[m << 4];

    // ---- stage 12ch x 6 tap-rows x (128 + 2 halo) cols, f32, coalesced ----
    {
        const int q = tid >> 5;
        const int l = tid & 31;
        #pragma unroll
        for (int j = 0; j < 9; ++j) {
            const int hr  = 8*j + q;               // 0..71 = (ch, tap-row)
            const int c   = hr / 6;
            const int r_  = hr - 6*c;
            const int row = (ra + 255 + r_) & 255;
            const f32x4 v = *reinterpret_cast<const f32x4*>(xb + c*NHW + (row << 8) + c0g + (l << 2));
            *reinterpret_cast<f32x4*>(&smem[c*CSTR + r_*RSTR + 4 + (l << 2)]) = v;
        }
        if (tid < 144) {
            const int hr  = tid >> 1;
            const int side= tid & 1;
            const int c   = hr / 6;
            const int r_  = hr - 6*c;
            const int row = (ra + 255 + r_) & 255;
            const int col = side ? ((c0g + 128) & 255) : ((c0g + 255) & 255);
            smem[c*CSTR + r_*RSTR + (side ? 132 : 3)] = xb[c*NHW + (row << 8) + col];
        }
    }
    __syncthreads();

    // ---- pipeline helpers (ref-param lambdas, fully inlined + const-indexed) ----
    auto LOADTAPS = [&](const int o, float (&t)[3][9]) {
        #pragma unroll
        for (int ci = 0; ci < 3; ++ci) {
            const int tbc = tb[ci] + o;
            t[ci][0] = smem[tbc+0];        t[ci][1] = smem[tbc+1];        t[ci][2] = smem[tbc+2];
            t[ci][3] = smem[tbc+RSTR];     t[ci][4] = smem[tbc+RSTR+1];   t[ci][5] = smem[tbc+RSTR+2];
            t[ci][6] = smem[tbc+2*RSTR];   t[ci][7] = smem[tbc+2*RSTR+1]; t[ci][8] = smem[tbc+2*RSTR+2];
        }
    };
    auto STENCIL = [&](const float (&t)[3][9], uint32_t (&yw)[6], float (&xm)[3]) {
        #pragma unroll
        for (int ci = 0; ci < 3; ++ci) {
            const float v0 = t[ci][0], v1 = t[ci][1], v2 = t[ci][2];
            const float v3 = t[ci][3], v4 = t[ci][4], v5 = t[ci][5];
            const float v6 = t[ci][6], v7 = t[ci][7], v8 = t[ci][8];
            const float s0 = v0 + v2, d0 = v2 - v0;
            const float s1 = v3 + v5, d1 = v5 - v3;
            const float s2 = v6 + v8, d2 = v8 - v6;
            const float t0 = fmaf(2.f, v1, s0);
            const float t2 = fmaf(2.f, v7, s2);
            const float fsx = fmaf(2.f, d1, d0 + d2);
            const float fsy = t2 - t0;
            const float lap = fmaf(-12.f, v4, fmaf(2.f, s1, t0 + t2));
            yw[2*ci]   = pkbf(v4, fsx);   // ident, sobel_x
            yw[2*ci+1] = pkbf(fsy, lap);  // sobel_xT, lap
            xm[ci] = v4;
        }
    };

    // prologue: body 0's taps + stencil
    uint32_t ywc[6]; float xmc[3];
    {
        float tc[3][9];
        LOADTAPS(0, tc);
        STENCIL(tc, ywc, xmc);
    }

    #pragma unroll
    for (int grp = 0; grp < 8; ++grp) {
        const int o = grp << 4;

        // issue next body's 27 ds_reads BEFORE this body's MFMAs
        float tn[3][9];
        if (grp < 7) LOADTAPS(o + 16, tn);

        const bf16x8 yf0 = __builtin_bit_cast(bf16x8, (u32x4){ywc[0], ywc[1], ywc[2], ywc[3]});
        const bf16x8 yf1 = __builtin_bit_cast(bf16x8, (u32x4){ywc[4], ywc[5], one_c, 0u});

        // ---- GEMM1 (bias in K, ReLU, pack); no scheduler fences ----
        uint32_t pu[6][2];
        #pragma unroll
        for (int t = 0; t < 6; ++t) {
            f32x4 acc = __builtin_amdgcn_mfma_f32_16x16x32_bf16(__builtin_bit_cast(bf16x8, a1u[t][0]), yf0, zacc, 0, 0, 0);
            acc = __builtin_amdgcn_mfma_f32_16x16x32_bf16(__builtin_bit_cast(bf16x8, a1u[t][1]), yf1, acc, 0, 0, 0);
            pu[t][0] = pkbf(fmaxf(acc[0], 0.f), fmaxf(acc[1], 0.f));
            pu[t][1] = pkbf(fmaxf(acc[2], 0.f), fmaxf(acc[3], 0.f));
        }

        // next body's stencil (VALU) in the MFMA shadow
        uint32_t ywn[6]; float xmn[3];
        if (grp < 7) STENCIL(tn, ywn, xmn);

        // ---- GEMM2: pu words ARE the B-frags under the K-bijection ----
        f32x4 acc2;
        #pragma unroll
        for (int s2 = 0; s2 < 3; ++s2) {
            const u32x4 fb2 = { pu[2*s2][0], pu[2*s2][1], pu[2*s2+1][0], pu[2*s2+1][1] };
            acc2 = __builtin_amdgcn_mfma_f32_16x16x32_bf16(__builtin_bit_cast(bf16x8, a2u[s2]), __builtin_bit_cast(bf16x8, fb2),
                                                           (s2 == 0) ? zacc : acc2, 0, 0, 0);
        }

        // ---- epilogue: prefetched mask, x from held center taps ----
        const float um = floorf(mv[grp] + 0.5f);
        #pragma unroll
        for (int r = 0; r < 3; ++r)
            obp[r][o] = xmc[r] + acc2[r] * um;

        // rotate pipeline regs (renamed away by full unroll)
        if (grp < 7) {
            #pragma unroll
            for (int i = 0; i < 6; ++i) ywc[i] = ywn[i];
            #pragma unroll
            for (int i = 0; i < 3; ++i) xmc[i] = xmn[i];
        }
    }
}

extern "C" void kernel_launch(void* const* d_in, const int* in_sizes, int n_in,
                              void* d_out, int out_size, void* d_ws, size_t ws_size,
                              hipStream_t stream) {
    const float* x  = (const float*)d_in[0];
    const float* w1 = (const float*)d_in[1];
    const float* b1 = (const float*)d_in[2];
    const float* w2 = (const float*)d_in[3];
    const float* rm = (const float*)d_in[4];
    float* out = (float*)d_out;
    nca_fused19<<<dim3(32 * 64 * 2), dim3(256), 0, stream>>>(x, w1, b1, w2, rm, out);
}

// Round 21
// 80.748 us; speedup vs baseline: 1.0071x; 1.0071x over previous
//
#include <hip/hip_runtime.h>
#include <stdint.h>

#define NC 12
#define NHW (256*256)
#define RSTR 136            // LDS floats per tap-row: [3]=haloL, [4..131]=cols, [132]=haloR
#define CSTR 816            // 6*RSTR; %32==16 -> tap reads 2-way (free, m136)

typedef __attribute__((ext_vector_type(8))) short bf16x8;
typedef __attribute__((ext_vector_type(4))) float f32x4;
typedef __attribute__((ext_vector_type(4))) uint32_t u32x4;
typedef __attribute__((ext_vector_type(2))) __bf16 bf16x2v;

// hot-path pack: single v_cvt_pk_bf16_f32
__device__ __forceinline__ uint32_t pkbf(float lo, float hi) {
    uint32_t r;
    asm("v_cvt_pk_bf16_f32 %0, %1, %2" : "=v"(r) : "v"(lo), "v"(hi));
    return r;
}
// cold-path pack (weight setup, once per block)
__device__ __forceinline__ uint32_t pkbf_c(float lo, float hi) {
    bf16x2v v = { (__bf16)lo, (__bf16)hi };
    return __builtin_bit_cast(uint32_t, v);
}
// opaque "v" pin (r6-verified). NEVER "a" (r12); NEVER (256,4) (r17 spill, r18 miscompile).
#define PIN(v) asm volatile("" : "+v"(v))

// Fused NCA step, LDS-staged 4x128 tile, 1-ahead software pipeline.
// == r19 (80.6us best) + per-block setup amortization: one block now processes
// BOTH column-halves of its row-strip (16 bodies instead of 8), so the
// weight-fragment build (21 global loads + ~42 cvt_pk per thread) runs half as
// often. Inter-half barrier is covered by the other resident blocks per CU;
// half-1 mask prefetch issues before the barrier to hide under it.
// K-bijections (same on A and B => contraction exact):
//   GEMM1 (w1[96x48]·yT): slot(s,g,j): s=0 -> col 12g+j ; s=1,j<4 -> col 12g+8+j
//   BIAS fold (r11-verified): slot (s=1,g=0,elem4): A=bf16(b1[row]), B=bf16(1.0)
//   GEMM2 (w2[12x96]·hT): slot(s2,g,j) -> col 32s2 + 16*(j>=4) + 4g + (j&3)
// GEMM1's D regs ARE GEMM2's B-frags. GEMM2 M-perm sigma(4g+r)=3g+r:
// acc2[r]'s channel == lane's stencil channel c0+r -> epilogue x = held center tap.
__global__ __launch_bounds__(256, 3) void nca_fused20(
    const float* __restrict__ x, const float* __restrict__ w1,
    const float* __restrict__ b1, const float* __restrict__ w2,
    const float* __restrict__ rmask, float* __restrict__ out)
{
    __shared__ float smem[12 * CSTR];   // 39168 B

    const int tid  = threadIdx.x;
    const int lane = tid & 63;
    const int wv   = tid >> 6;
    const int g    = lane >> 4;   // 16-lane group
    const int p    = lane & 15;   // pixel col (B/D), weight row (A)
    const int c0   = 3 * g;       // lane's stencil/epilogue channel base

    // ---- weight fragments (bias folded into a1u[t][1] elem4), "v"-pinned ----
    u32x4 a1u[6][2];
    #pragma unroll
    for (int t = 0; t < 6; ++t) {
        const int row = 16*t + p;
        const float4 fa = *reinterpret_cast<const float4*>(w1 + row*48 + 12*g + 0);
        const float4 fb = *reinterpret_cast<const float4*>(w1 + row*48 + 12*g + 4);
        const float4 fc = *reinterpret_cast<const float4*>(w1 + row*48 + 12*g + 8);
        const uint32_t biasw = (g == 0) ? pkbf_c(b1[row], 0.f) : 0u;
        a1u[t][0] = (u32x4){ pkbf_c(fa.x, fa.y), pkbf_c(fa.z, fa.w), pkbf_c(fb.x, fb.y), pkbf_c(fb.z, fb.w) };
        a1u[t][1] = (u32x4){ pkbf_c(fc.x, fc.y), pkbf_c(fc.z, fc.w), biasw, 0u };
        PIN(a1u[t][0]); PIN(a1u[t][1]);
    }
    u32x4 a2u[3];
    {
        const int rp = p & 3, gp = p >> 2;
        const int chA = 3*gp + rp;              // sigma(4g+r)=3g+r
        #pragma unroll
        for (int s = 0; s < 3; ++s) {
            u32x4 u = {0u, 0u, 0u, 0u};
            if (rp < 3) {
                const float4 wa = *reinterpret_cast<const float4*>(w2 + chA*96 + 32*s + 4*g);
                const float4 wb = *reinterpret_cast<const float4*>(w2 + chA*96 + 32*s + 16 + 4*g);
                u = (u32x4){ pkbf_c(wa.x, wa.y), pkbf_c(wa.z, wa.w), pkbf_c(wb.x, wb.y), pkbf_c(wb.z, wb.w) };
            }
            a2u[s] = u;
            PIN(a2u[s]);
        }
    }
    const uint32_t one_c = (g == 0) ? 0x00003F80u : 0u;   // elem4 = bf16(1.0), group 0

    // shared zero C-in quad (r19)
    f32x4 zacc = {0.f, 0.f, 0.f, 0.f};
    PIN(zacc);

    // grid: 2048 blocks = 32 batches x 64 row-strips; block does BOTH col-halves
    const int b     = blockIdx.x >> 6;
    const int strip = blockIdx.x & 63;
    const int ra    = strip << 2;
    const float* __restrict__ xb = x + (size_t)b * NC * NHW;
    const float* __restrict__ mb = rmask + (size_t)b * NHW;
    float* __restrict__ ob = out + (size_t)b * NC * NHW;

    // wave wv owns output row ra+wv
    const int h    = ra + wv;
    const int hrow = h << 8;

    // tile-local tap bases (same for both halves)
    int tb[3];
    #pragma unroll
    for (int ci = 0; ci < 3; ++ci) tb[ci] = (c0 + ci)*CSTR + wv*RSTR + 3 + p;

    #pragma unroll 1
    for (int hf = 0; hf < 2; ++hf) {
        const int c0g = hf << 7;

        // per-half bases + mask prefetch (issued BEFORE the inter-half barrier)
        float* obp[3];
        #pragma unroll
        for (int r = 0; r < 3; ++r) obp[r] = ob + (c0 + r)*NHW + hrow + c0g + p;
        const float* mbp = mb + hrow + c0g + p;
        float mv[8];
        #pragma unroll
        for (int m = 0; m < 8; ++m) mv[m] = mbp[m << 4];

        if (hf) __syncthreads();   // all waves done reading half-0 taps

        // ---- stage 12ch x 6 tap-rows x (128 + 2 halo) cols, f32, coalesced ----
        {
            const int q = tid >> 5;
            const int l = tid & 31;
            #pragma unroll
            for (int j = 0; j < 9; ++j) {
                const int hr  = 8*j + q;               // 0..71 = (ch, tap-row)
                const int c   = hr / 6;
                const int r_  = hr - 6*c;
                const int row = (ra + 255 + r_) & 255;
                const f32x4 v = *reinterpret_cast<const f32x4*>(xb + c*NHW + (row << 8) + c0g + (l << 2));
                *reinterpret_cast<f32x4*>(&smem[c*CSTR + r_*RSTR + 4 + (l << 2)]) = v;
            }
            if (tid < 144) {
                const int hr  = tid >> 1;
                const int side= tid & 1;
                const int c   = hr / 6;
                const int r_  = hr - 6*c;
                const int row = (ra + 255 + r_) & 255;
                const int col = side ? ((c0g + 128) & 255) : ((c0g + 255) & 255);
                smem[c*CSTR + r_*RSTR + (side ? 132 : 3)] = xb[c*NHW + (row << 8) + col];
            }
        }
        __syncthreads();

        // ---- pipeline helpers (fully inlined, const-indexed) ----
        auto LOADTAPS = [&](const int o, float (&t)[3][9]) {
            #pragma unroll
            for (int ci = 0; ci < 3; ++ci) {
                const int tbc = tb[ci] + o;
                t[ci][0] = smem[tbc+0];        t[ci][1] = smem[tbc+1];        t[ci][2] = smem[tbc+2];
                t[ci][3] = smem[tbc+RSTR];     t[ci][4] = smem[tbc+RSTR+1];   t[ci][5] = smem[tbc+RSTR+2];
                t[ci][6] = smem[tbc+2*RSTR];   t[ci][7] = smem[tbc+2*RSTR+1]; t[ci][8] = smem[tbc+2*RSTR+2];
            }
        };
        auto STENCIL = [&](const float (&t)[3][9], uint32_t (&yw)[6], float (&xm)[3]) {
            #pragma unroll
            for (int ci = 0; ci < 3; ++ci) {
                const float v0 = t[ci][0], v1 = t[ci][1], v2 = t[ci][2];
                const float v3 = t[ci][3], v4 = t[ci][4], v5 = t[ci][5];
                const float v6 = t[ci][6], v7 = t[ci][7], v8 = t[ci][8];
                const float s0 = v0 + v2, d0 = v2 - v0;
                const float s1 = v3 + v5, d1 = v5 - v3;
                const float s2 = v6 + v8, d2 = v8 - v6;
                const float t0 = fmaf(2.f, v1, s0);
                const float t2 = fmaf(2.f, v7, s2);
                const float fsx = fmaf(2.f, d1, d0 + d2);
                const float fsy = t2 - t0;
                const float lap = fmaf(-12.f, v4, fmaf(2.f, s1, t0 + t2));
                yw[2*ci]   = pkbf(v4, fsx);   // ident, sobel_x
                yw[2*ci+1] = pkbf(fsy, lap);  // sobel_xT, lap
                xm[ci] = v4;
            }
        };

        // prologue: body 0's taps + stencil
        uint32_t ywc[6]; float xmc[3];
        {
            float tc[3][9];
            LOADTAPS(0, tc);
            STENCIL(tc, ywc, xmc);
        }

        #pragma unroll
        for (int grp = 0; grp < 8; ++grp) {
            const int o = grp << 4;

            // issue next body's 27 ds_reads BEFORE this body's MFMAs
            float tn[3][9];
            if (grp < 7) LOADTAPS(o + 16, tn);

            const bf16x8 yf0 = __builtin_bit_cast(bf16x8, (u32x4){ywc[0], ywc[1], ywc[2], ywc[3]});
            const bf16x8 yf1 = __builtin_bit_cast(bf16x8, (u32x4){ywc[4], ywc[5], one_c, 0u});

            // ---- GEMM1 (bias in K, ReLU, pack); C-in = shared zero quad ----
            __builtin_amdgcn_s_setprio(1);
            uint32_t pu[6][2];
            #pragma unroll
            for (int t = 0; t < 6; ++t) {
                f32x4 acc = __builtin_amdgcn_mfma_f32_16x16x32_bf16(__builtin_bit_cast(bf16x8, a1u[t][0]), yf0, zacc, 0, 0, 0);
                acc = __builtin_amdgcn_mfma_f32_16x16x32_bf16(__builtin_bit_cast(bf16x8, a1u[t][1]), yf1, acc, 0, 0, 0);
                pu[t][0] = pkbf(fmaxf(acc[0], 0.f), fmaxf(acc[1], 0.f));
                pu[t][1] = pkbf(fmaxf(acc[2], 0.f), fmaxf(acc[3], 0.f));
            }
            __builtin_amdgcn_s_setprio(0);

            // next body's stencil (VALU) in the MFMA shadow
            uint32_t ywn[6]; float xmn[3];
            if (grp < 7) STENCIL(tn, ywn, xmn);

            // ---- GEMM2: pu words ARE the B-frags under the K-bijection ----
            __builtin_amdgcn_s_setprio(1);
            f32x4 acc2;
            #pragma unroll
            for (int s2 = 0; s2 < 3; ++s2) {
                const u32x4 fb2 = { pu[2*s2][0], pu[2*s2][1], pu[2*s2+1][0], pu[2*s2+1][1] };
                acc2 = __builtin_amdgcn_mfma_f32_16x16x32_bf16(__builtin_bit_cast(bf16x8, a2u[s2]), __builtin_bit_cast(bf16x8, fb2),
                                                               (s2 == 0) ? zacc : acc2, 0, 0, 0);
            }
            __builtin_amdgcn_s_setprio(0);

            // ---- epilogue: prefetched mask, x from held center taps ----
            const float um = floorf(mv[grp] + 0.5f);
            #pragma unroll
            for (int r = 0; r < 3; ++r)
                obp[r][o] = xmc[r] + acc2[r] * um;

            // rotate pipeline regs (renamed away by full unroll)
            if (grp < 7) {
                #pragma unroll
                for (int i = 0; i < 6; ++i) ywc[i] = ywn[i];
                #pragma unroll
                for (int i = 0; i < 3; ++i) xmc[i] = xmn[i];
            }
        }
    }
}

extern "C" void kernel_launch(void* const* d_in, const int* in_sizes, int n_in,
                              void* d_out, int out_size, void* d_ws, size_t ws_size,
                              hipStream_t stream) {
    const float* x  = (const float*)d_in[0];
    const float* w1 = (const float*)d_in[1];
    const float* b1 = (const float*)d_in[2];
    const float* w2 = (const float*)d_in[3];
    const float* rm = (const float*)d_in[4];
    float* out = (float*)d_out;
    nca_fused20<<<dim3(32 * 64), dim3(256), 0, stream>>>(x, w1, b1, w2, rm, out);
}

// Round 22
// 79.755 us; speedup vs baseline: 1.0196x; 1.0124x over previous
//
#include <hip/hip_runtime.h>
#include <stdint.h>

#define NC 12
#define NHW (256*256)
#define RSTR 136            // LDS floats per tap-row: [3]=haloL, [4..131]=cols, [132]=haloR
#define CSTR 816            // 6*RSTR; %32==16 -> tap reads 2-way (free, m136)

typedef __attribute__((ext_vector_type(8))) short bf16x8;
typedef __attribute__((ext_vector_type(4))) float f32x4;
typedef __attribute__((ext_vector_type(4))) uint32_t u32x4;
typedef __attribute__((ext_vector_type(2))) __bf16 bf16x2v;

// hot-path pack: single v_cvt_pk_bf16_f32
__device__ __forceinline__ uint32_t pkbf(float lo, float hi) {
    uint32_t r;
    asm("v_cvt_pk_bf16_f32 %0, %1, %2" : "=v"(r) : "v"(lo), "v"(hi));
    return r;
}
// cold-path pack (weight setup, once)
__device__ __forceinline__ uint32_t pkbf_c(float lo, float hi) {
    bf16x2v v = { (__bf16)lo, (__bf16)hi };
    return __builtin_bit_cast(uint32_t, v);
}

// Fused NCA step, LDS-staged 4x128 tile, 1-ahead software pipeline.
// == r19 (80.6us) with ALL PIN pins REMOVED — single-variable diagnostic of the
// AGPR-split theory: VGPR_Count=84 can't hold 60 pinned weight regs + ~60-float
// tap live set, so the allocator splits across AGPRs; if that split costs
// v_accvgpr shuttles it explains the measured 2.5x VALU amplification. The "v"
// pins themselves may force the split. Without pins, either (a) everything
// lands in arch VGPRs (VGPR->~140, dur down) or (b) r4-era remat returns
// (FETCH up, dur up) -> PIN is load-bearing and r19 is final.
// K-bijections (same on A and B => contraction exact):
//   GEMM1 (w1[96x48]·yT): slot(s,g,j): s=0 -> col 12g+j ; s=1,j<4 -> col 12g+8+j
//   BIAS fold (r11-verified): slot (s=1,g=0,elem4): A=bf16(b1[row]), B=bf16(1.0)
//   GEMM2 (w2[12x96]·hT): slot(s2,g,j) -> col 32s2 + 16*(j>=4) + 4g + (j&3)
// GEMM1's D regs ARE GEMM2's B-frags. GEMM2 M-perm sigma(4g+r)=3g+r:
// acc2[r]'s channel == lane's stencil channel c0+r -> epilogue x = held center tap.
__global__ __launch_bounds__(256, 3) void nca_fused21(
    const float* __restrict__ x, const float* __restrict__ w1,
    const float* __restrict__ b1, const float* __restrict__ w2,
    const float* __restrict__ rmask, float* __restrict__ out)
{
    __shared__ float smem[12 * CSTR];   // 39168 B

    const int tid  = threadIdx.x;
    const int lane = tid & 63;
    const int wv   = tid >> 6;
    const int g    = lane >> 4;   // 16-lane group
    const int p    = lane & 15;   // pixel col (B/D), weight row (A)
    const int c0   = 3 * g;       // lane's stencil/epilogue channel base

    // ---- weight fragments (bias folded into a1u[t][1] elem4) — NO pins ----
    u32x4 a1u[6][2];
    #pragma unroll
    for (int t = 0; t < 6; ++t) {
        const int row = 16*t + p;
        const float4 fa = *reinterpret_cast<const float4*>(w1 + row*48 + 12*g + 0);
        const float4 fb = *reinterpret_cast<const float4*>(w1 + row*48 + 12*g + 4);
        const float4 fc = *reinterpret_cast<const float4*>(w1 + row*48 + 12*g + 8);
        const uint32_t biasw = (g == 0) ? pkbf_c(b1[row], 0.f) : 0u;
        a1u[t][0] = (u32x4){ pkbf_c(fa.x, fa.y), pkbf_c(fa.z, fa.w), pkbf_c(fb.x, fb.y), pkbf_c(fb.z, fb.w) };
        a1u[t][1] = (u32x4){ pkbf_c(fc.x, fc.y), pkbf_c(fc.z, fc.w), biasw, 0u };
    }
    u32x4 a2u[3];
    {
        const int rp = p & 3, gp = p >> 2;
        const int chA = 3*gp + rp;              // sigma(4g+r)=3g+r
        #pragma unroll
        for (int s = 0; s < 3; ++s) {
            u32x4 u = {0u, 0u, 0u, 0u};
            if (rp < 3) {
                const float4 wa = *reinterpret_cast<const float4*>(w2 + chA*96 + 32*s + 4*g);
                const float4 wb = *reinterpret_cast<const float4*>(w2 + chA*96 + 32*s + 16 + 4*g);
                u = (u32x4){ pkbf_c(wa.x, wa.y), pkbf_c(wa.z, wa.w), pkbf_c(wb.x, wb.y), pkbf_c(wb.z, wb.w) };
            }
            a2u[s] = u;
        }
    }
    const uint32_t one_c = (g == 0) ? 0x00003F80u : 0u;   // elem4 = bf16(1.0), group 0

    // shared zero C-in quad (r19)
    const f32x4 zacc = {0.f, 0.f, 0.f, 0.f};

    // grid: 4096 blocks = 32 batches x 64 row-strips x 2 col-halves
    const int b     = blockIdx.x >> 7;
    const int strip = (blockIdx.x >> 1) & 63;
    const int half  = blockIdx.x & 1;
    const int ra    = strip << 2;
    const int c0g   = half << 7;
    const float* __restrict__ xb = x + (size_t)b * NC * NHW;
    const float* __restrict__ mb = rmask + (size_t)b * NHW;
    float* __restrict__ ob = out + (size_t)b * NC * NHW;

    // wave wv owns output row ra+wv
    const int h    = ra + wv;
    const int hrow = h << 8;

    // hoisted bases (before staging so mask prefetch can issue first)
    int tb[3];
    #pragma unroll
    for (int ci = 0; ci < 3; ++ci) tb[ci] = (c0 + ci)*CSTR + wv*RSTR + 3 + p;
    float* obp[3];
    #pragma unroll
    for (int r = 0; r < 3; ++r) obp[r] = ob + (c0 + r)*NHW + hrow + c0g + p;
    const float* mbp = mb + hrow + c0g + p;

    // ---- prefetch ALL 8 mask values (global, ~900cy) before anything else ----
    float mv[8];
    #pragma unroll
    for (int m = 0; m < 8; ++m) mv[m] = mbp[m << 4];

    // ---- stage 12ch x 6 tap-rows x (128 + 2 halo) cols, f32, coalesced ----
    {
        const int q = tid >> 5;
        const int l = tid & 31;
        #pragma unroll
        for (int j = 0; j < 9; ++j) {
            const int hr  = 8*j + q;               // 0..71 = (ch, tap-row)
            const int c   = hr / 6;
            const int r_  = hr - 6*c;
            const int row = (ra + 255 + r_) & 255;
            const f32x4 v = *reinterpret_cast<const f32x4*>(xb + c*NHW + (row << 8) + c0g + (l << 2));
            *reinterpret_cast<f32x4*>(&smem[c*CSTR + r_*RSTR + 4 + (l << 2)]) = v;
        }
        if (tid < 144) {
            const int hr  = tid >> 1;
            const int side= tid & 1;
            const int c   = hr / 6;
            const int r_  = hr - 6*c;
            const int row = (ra + 255 + r_) & 255;
            const int col = side ? ((c0g + 128) & 255) : ((c0g + 255) & 255);
            smem[c*CSTR + r_*RSTR + (side ? 132 : 3)] = xb[c*NHW + (row << 8) + col];
        }
    }
    __syncthreads();

    // ---- pipeline helpers (ref-param lambdas, fully inlined + const-indexed) ----
    auto LOADTAPS = [&](const int o, float (&t)[3][9]) {
        #pragma unroll
        for (int ci = 0; ci < 3; ++ci) {
            const int tbc = tb[ci] + o;
            t[ci][0] = smem[tbc+0];        t[ci][1] = smem[tbc+1];        t[ci][2] = smem[tbc+2];
            t[ci][3] = smem[tbc+RSTR];     t[ci][4] = smem[tbc+RSTR+1];   t[ci][5] = smem[tbc+RSTR+2];
            t[ci][6] = smem[tbc+2*RSTR];   t[ci][7] = smem[tbc+2*RSTR+1]; t[ci][8] = smem[tbc+2*RSTR+2];
        }
    };
    auto STENCIL = [&](const float (&t)[3][9], uint32_t (&yw)[6], float (&xm)[3]) {
        #pragma unroll
        for (int ci = 0; ci < 3; ++ci) {
            const float v0 = t[ci][0], v1 = t[ci][1], v2 = t[ci][2];
            const float v3 = t[ci][3], v4 = t[ci][4], v5 = t[ci][5];
            const float v6 = t[ci][6], v7 = t[ci][7], v8 = t[ci][8];
            const float s0 = v0 + v2, d0 = v2 - v0;
            const float s1 = v3 + v5, d1 = v5 - v3;
            const float s2 = v6 + v8, d2 = v8 - v6;
            const float t0 = fmaf(2.f, v1, s0);
            const float t2 = fmaf(2.f, v7, s2);
            const float fsx = fmaf(2.f, d1, d0 + d2);
            const float fsy = t2 - t0;
            const float lap = fmaf(-12.f, v4, fmaf(2.f, s1, t0 + t2));
            yw[2*ci]   = pkbf(v4, fsx);   // ident, sobel_x
            yw[2*ci+1] = pkbf(fsy, lap);  // sobel_xT, lap
            xm[ci] = v4;
        }
    };

    // prologue: body 0's taps + stencil
    uint32_t ywc[6]; float xmc[3];
    {
        float tc[3][9];
        LOADTAPS(0, tc);
        STENCIL(tc, ywc, xmc);
    }

    #pragma unroll
    for (int grp = 0; grp < 8; ++grp) {
        const int o = grp << 4;

        // issue next body's 27 ds_reads BEFORE this body's MFMAs
        float tn[3][9];
        if (grp < 7) LOADTAPS(o + 16, tn);

        const bf16x8 yf0 = __builtin_bit_cast(bf16x8, (u32x4){ywc[0], ywc[1], ywc[2], ywc[3]});
        const bf16x8 yf1 = __builtin_bit_cast(bf16x8, (u32x4){ywc[4], ywc[5], one_c, 0u});

        // ---- GEMM1 (bias in K, ReLU, pack); C-in = shared zero quad ----
        __builtin_amdgcn_s_setprio(1);
        uint32_t pu[6][2];
        #pragma unroll
        for (int t = 0; t < 6; ++t) {
            f32x4 acc = __builtin_amdgcn_mfma_f32_16x16x32_bf16(__builtin_bit_cast(bf16x8, a1u[t][0]), yf0, zacc, 0, 0, 0);
            acc = __builtin_amdgcn_mfma_f32_16x16x32_bf16(__builtin_bit_cast(bf16x8, a1u[t][1]), yf1, acc, 0, 0, 0);
            pu[t][0] = pkbf(fmaxf(acc[0], 0.f), fmaxf(acc[1], 0.f));
            pu[t][1] = pkbf(fmaxf(acc[2], 0.f), fmaxf(acc[3], 0.f));
        }
        __builtin_amdgcn_s_setprio(0);

        // next body's stencil (VALU) in the MFMA shadow
        uint32_t ywn[6]; float xmn[3];
        if (grp < 7) STENCIL(tn, ywn, xmn);

        // ---- GEMM2: pu words ARE the B-frags under the K-bijection ----
        __builtin_amdgcn_s_setprio(1);
        f32x4 acc2;
        #pragma unroll
        for (int s2 = 0; s2 < 3; ++s2) {
            const u32x4 fb2 = { pu[2*s2][0], pu[2*s2][1], pu[2*s2+1][0], pu[2*s2+1][1] };
            acc2 = __builtin_amdgcn_mfma_f32_16x16x32_bf16(__builtin_bit_cast(bf16x8, a2u[s2]), __builtin_bit_cast(bf16x8, fb2),
                                                           (s2 == 0) ? zacc : acc2, 0, 0, 0);
        }
        __builtin_amdgcn_s_setprio(0);

        // ---- epilogue: prefetched mask, x from held center taps ----
        const float um = floorf(mv[grp] + 0.5f);
        #pragma unroll
        for (int r = 0; r < 3; ++r)
            obp[r][o] = xmc[r] + acc2[r] * um;

        // rotate pipeline regs (renamed away by full unroll)
        if (grp < 7) {
            #pragma unroll
            for (int i = 0; i < 6; ++i) ywc[i] = ywn[i];
            #pragma unroll
            for (int i = 0; i < 3; ++i) xmc[i] = xmn[i];
        }
    }
}

extern "C" void kernel_launch(void* const* d_in, const int* in_sizes, int n_in,
                              void* d_out, int out_size, void* d_ws, size_t ws_size,
                              hipStream_t stream) {
    const float* x  = (const float*)d_in[0];
    const float* w1 = (const float*)d_in[1];
    const float* b1 = (const float*)d_in[2];
    const float* w2 = (const float*)d_in[3];
    const float* rm = (const float*)d_in[4];
    float* out = (float*)d_out;
    nca_fused21<<<dim3(32 * 64 * 2), dim3(256), 0, stream>>>(x, w1, b1, w2, rm, out);
}